// Round 1
// baseline (108.066 us; speedup 1.0000x reference)
//
#include <hip/hip_runtime.h>
#include <math.h>

#define NT 50      // num event types
#define ND 4       // num decays
#define NB 4       // batch
#define NN 2048    // events per batch
#define NN_LOG2 11

// Workspace layout (float offsets)
#define OFF_A        0          // Ahat: NT*NT*ND = 10000
#define OFF_MHAT     10000      // mhat: 50
#define OFF_OMEGA    10052      // omega: 4
#define OFF_SUMMHAT  10056      // scalar
#define OFF_COLSUM   10060      // colsum[c][d]: NT*ND = 200
#define OFF_ROWLL    10304      // per-event log-rate*mask: NB*NN = 8192
#define OFF_ROWCOMP  18496      // per-event compensator*mask: NB*NN = 8192
// total 26688 floats = ~104 KB

__device__ __forceinline__ float softplus_stable(float x) {
    // matches jax.nn.softplus: max(x,0) + log1p(exp(-|x|))
    return fmaxf(x, 0.0f) + log1pf(expf(-fabsf(x)));
}

// ---------------- Kernel A: parameter prep (1 block) ----------------
__global__ __launch_bounds__(256) void prep_kernel(
        const float* __restrict__ mu_p,
        const float* __restrict__ alpha_p,
        const float* __restrict__ beta_p,
        float* __restrict__ ws) {
    int tid = threadIdx.x;
    // Ahat = softplus(alpha_p), 10000 entries
    for (int t = tid; t < NT * NT * ND; t += 256)
        ws[OFF_A + t] = softplus_stable(alpha_p[t]);
    // mhat
    for (int t = tid; t < NT; t += 256)
        ws[OFF_MHAT + t] = softplus_stable(mu_p[t]);
    // omega
    if (tid < ND)
        ws[OFF_OMEGA + tid] = softplus_stable(beta_p[tid]);
    __syncthreads();
    // colsum[c][d] = sum_k Ahat[k][c][d]
    for (int t = tid; t < NT * ND; t += 256) {
        float s = 0.0f;
        for (int k = 0; k < NT; ++k)
            s += ws[OFF_A + k * (NT * ND) + t];
        ws[OFF_COLSUM + t] = s;
    }
    if (tid == 0) {
        float s = 0.0f;
        for (int k = 0; k < NT; ++k) s += ws[OFF_MHAT + k];
        ws[OFF_SUMMHAT] = s;
    }
}

// ---------------- Kernel B: per-event rate + compensator term ----------------
__global__ __launch_bounds__(256) void rates_kernel(
        const float* __restrict__ times,
        const int*   __restrict__ types,
        const float* __restrict__ mask,
        const float* __restrict__ t1,
        float* __restrict__ ws) {
    __shared__ __align__(16) float Arow[NT * ND];   // Ahat[type_i, :, :]
    __shared__ float wsum[4];

    int blk = blockIdx.x;
    int b = blk >> NN_LOG2;
    int i = blk & (NN - 1);
    int base = b * NN;

    int   ty_i = types[base + i];
    float t_i  = times[base + i];

    // stage this row's Ahat slice: Arow[c*4+d] = Ahat[ty_i][c][d]
    for (int t = threadIdx.x; t < NT * ND; t += 256)
        Arow[t] = ws[OFF_A + ty_i * (NT * ND) + t];

    float w0 = ws[OFF_OMEGA + 0];
    float w1 = ws[OFF_OMEGA + 1];
    float w2 = ws[OFF_OMEGA + 2];
    float w3 = ws[OFF_OMEGA + 3];
    __syncthreads();

    float a0 = 0.f, a1 = 0.f, a2 = 0.f, a3 = 0.f;
    for (int j = threadIdx.x; j < i; j += 256) {
        float tj = times[base + j];
        int   c  = types[base + j];
        float dt = t_i - tj;
        float e0 = __expf(-w0 * dt);
        float e1 = __expf(-w1 * dt);
        float e2 = __expf(-w2 * dt);
        float e3 = __expf(-w3 * dt);
        float4 av = *(const float4*)&Arow[c * 4];
        a0 = fmaf(av.x, e0, a0);
        a1 = fmaf(av.y, e1, a1);
        a2 = fmaf(av.z, e2, a2);
        a3 = fmaf(av.w, e3, a3);
    }
    float partial = w0 * a0 + w1 * a1 + w2 * a2 + w3 * a3;

    // block reduction: wave64 shuffle then LDS across the 4 waves
    #pragma unroll
    for (int off = 32; off > 0; off >>= 1)
        partial += __shfl_down(partial, off, 64);
    int lane = threadIdx.x & 63;
    int wid  = threadIdx.x >> 6;
    if (lane == 0) wsum[wid] = partial;
    __syncthreads();

    if (threadIdx.x == 0) {
        float tot = wsum[0] + wsum[1] + wsum[2] + wsum[3];
        float m   = mask[base + i];
        float rate = ws[OFF_MHAT + ty_i] + tot;
        ws[OFF_ROWLL + base + i] = logf(rate + 1e-8f) * m;

        // compensator contribution of event i:
        // sum_d colsum[ty_i][d] * (1 - exp(-omega_d * (t1[b] - t_i)))
        float tt = t1[b] - t_i;
        float comp =
            ws[OFF_COLSUM + ty_i * ND + 0] * (1.0f - __expf(-w0 * tt)) +
            ws[OFF_COLSUM + ty_i * ND + 1] * (1.0f - __expf(-w1 * tt)) +
            ws[OFF_COLSUM + ty_i * ND + 2] * (1.0f - __expf(-w2 * tt)) +
            ws[OFF_COLSUM + ty_i * ND + 3] * (1.0f - __expf(-w3 * tt));
        ws[OFF_ROWCOMP + base + i] = comp * m;
    }
}

// ---------------- Kernel C: final reduction (NB blocks) ----------------
__global__ __launch_bounds__(256) void finalize_kernel(
        const float* __restrict__ t0,
        const float* __restrict__ t1,
        const float* __restrict__ ws,
        float* __restrict__ out) {
    __shared__ float sll[4];
    __shared__ float scp[4];
    int b = blockIdx.x;
    int base = b * NN;

    float s_ll = 0.f, s_cp = 0.f;
    for (int j = threadIdx.x; j < NN; j += 256) {
        s_ll += ws[OFF_ROWLL + base + j];
        s_cp += ws[OFF_ROWCOMP + base + j];
    }
    #pragma unroll
    for (int off = 32; off > 0; off >>= 1) {
        s_ll += __shfl_down(s_ll, off, 64);
        s_cp += __shfl_down(s_cp, off, 64);
    }
    int lane = threadIdx.x & 63;
    int wid  = threadIdx.x >> 6;
    if (lane == 0) { sll[wid] = s_ll; scp[wid] = s_cp; }
    __syncthreads();
    if (threadIdx.x == 0) {
        float ll = sll[0] + sll[1] + sll[2] + sll[3];
        float cp = scp[0] + scp[1] + scp[2] + scp[3];
        out[b]      = ll;
        out[NB + b] = (t1[b] - t0[b]) * ws[OFF_SUMMHAT] + cp;
    }
}

extern "C" void kernel_launch(void* const* d_in, const int* in_sizes, int n_in,
                              void* d_out, int out_size, void* d_ws, size_t ws_size,
                              hipStream_t stream) {
    const float* times  = (const float*)d_in[0];
    const int*   types  = (const int*)  d_in[1];
    const float* mask   = (const float*)d_in[2];
    const float* t0     = (const float*)d_in[3];
    const float* t1     = (const float*)d_in[4];
    const float* mu_p   = (const float*)d_in[5];
    const float* alpha_p= (const float*)d_in[6];
    const float* beta_p = (const float*)d_in[7];
    float* out = (float*)d_out;
    float* ws  = (float*)d_ws;

    prep_kernel<<<1, 256, 0, stream>>>(mu_p, alpha_p, beta_p, ws);
    rates_kernel<<<NB * NN, 256, 0, stream>>>(times, types, mask, t1, ws);
    finalize_kernel<<<NB, 256, 0, stream>>>(t0, t1, ws, out);
}